// Round 19
// baseline (545.139 us; speedup 1.0000x reference)
//
#include <hip/hip_runtime.h>
#include <hip/hip_bf16.h>

// SpectralMoleculeEncoder: 3-layer ChebConv (K=3), N=50000, E=800000, 32->128->256->512.
// R19 = R18 + slim edge records: store only esrc (4B/edge, was 8B EdgeRec); weight
// w = -dinv[s]*dinv[d] recomputed per use (dinv_d hoisted per node; dinv[] is 200KB,
// L2-resident everywhere -> extra 4B load is a hit). Same f32 ops/order as fill_kernel
// -> bit-identical (canary 0.03125). Edge stream per prop pass halves (26 passes x
// 6.4MB -> x 3.2MB = 166->83MB of L3 traffic). All else = R18 (best, 430.5us).

typedef __bf16 bf16x8 __attribute__((ext_vector_type(8)));
typedef float f32x4 __attribute__((ext_vector_type(4)));
typedef unsigned short ushort_t;

__device__ inline float bf2f(ushort_t u) { return __builtin_bit_cast(float, (unsigned)u << 16); }
__device__ inline ushort_t f2bf(float f) { return __builtin_bit_cast(ushort_t, (__bf16)f); }

union U8 { int4 v; ushort_t u[8]; };

__device__ inline void gload16(const ushort_t* g, ushort_t* l) {
    __builtin_amdgcn_global_load_lds(
        (const __attribute__((address_space(1))) unsigned int*)g,
        (__attribute__((address_space(3))) unsigned int*)l, 16, 0, 0);
}

// ---------------- graph build ----------------
__global__ void count_kernel(const int* __restrict__ src, const int* __restrict__ dst,
                             int* __restrict__ cnt_src, int* __restrict__ cnt_dst, int E, int N) {
    int e = blockIdx.x * blockDim.x + threadIdx.x;
    if (e >= E) return;
    int s = src[e], d = dst[e];
    if ((unsigned)s < (unsigned)N) atomicAdd(&cnt_src[s], 1);
    if ((unsigned)d < (unsigned)N) atomicAdd(&cnt_dst[d], 1);
}

// ---- hierarchical exclusive scan of cnt[N] -> row_ptr[N+1], wofs[N] ----
__global__ void blocksum_kernel(const int* __restrict__ cnt, int* __restrict__ bsum, int N) {
    int i = blockIdx.x * 256 + threadIdx.x;
    int v = (i < N) ? cnt[i] : 0;
#pragma unroll
    for (int off = 32; off >= 1; off >>= 1) v += __shfl_xor(v, off);
    __shared__ int ws[4];
    if ((threadIdx.x & 63) == 0) ws[threadIdx.x >> 6] = v;
    __syncthreads();
    if (threadIdx.x == 0) bsum[blockIdx.x] = ws[0] + ws[1] + ws[2] + ws[3];
}

__global__ void scanblock_kernel(const int* __restrict__ arr, int* __restrict__ out, int nb) {
    __shared__ int s[256];
    int t = threadIdx.x;
    int v = (t < nb) ? arr[t] : 0;
    s[t] = v;
    __syncthreads();
#pragma unroll
    for (int off = 1; off < 256; off <<= 1) {
        int u = (t >= off) ? s[t - off] : 0;
        __syncthreads();
        s[t] += u;
        __syncthreads();
    }
    if (t < nb) out[t] = s[t] - v;  // exclusive
}

// fused: scan-scatter for row_ptr/wofs + dinv (from cnt_src)
__global__ void scatter_scan_kernel(const int* __restrict__ cnt, const int* __restrict__ boff,
                                    const int* __restrict__ cnt_src, float* __restrict__ dinv,
                                    int* __restrict__ row_ptr, int* __restrict__ wofs, int N) {
    __shared__ int s[256];
    int t = threadIdx.x;
    int i = blockIdx.x * 256 + t;
    int v = (i < N) ? cnt[i] : 0;
    s[t] = v;
    __syncthreads();
#pragma unroll
    for (int off = 1; off < 256; off <<= 1) {
        int u = (t >= off) ? s[t - off] : 0;
        __syncthreads();
        s[t] += u;
        __syncthreads();
    }
    int run = boff[blockIdx.x] + s[t] - v;
    if (i < N) {
        row_ptr[i] = run; wofs[i] = run;
        int c = cnt_src[i];
        dinv[i] = (c > 0) ? rsqrtf((float)c) : 0.0f;
    } else if (i == N) row_ptr[N] = run;
}

// fill: store ONLY the source index (4B/edge); weight recomputed in prop.
__global__ void fill_kernel(const int* __restrict__ src, const int* __restrict__ dst,
                            int* __restrict__ wofs, int* __restrict__ esrc, int E, int N) {
    int e = blockIdx.x * blockDim.x + threadIdx.x;
    if (e >= E) return;
    int s = src[e], d = dst[e];
    if ((unsigned)s >= (unsigned)N || (unsigned)d >= (unsigned)N) return;
    int pos = atomicAdd(&wofs[d], 1);
    esrc[pos] = s;
}

// v [N,32] f32 -> txb1 slice0 (chunk-major, NC=1 == [N][32]) bf16
__global__ void convin_kernel(const float* __restrict__ v, ushort_t* __restrict__ txb, int N) {
    int id = blockIdx.x * blockDim.x + threadIdx.x;
    if (id >= N * 4) return;
    int node = id >> 2, c = (id & 3) << 3;
    const float* p = &v[(size_t)node * 32 + c];
    U8 o;
#pragma unroll
    for (int i = 0; i < 8; ++i) o.u[i] = f2bf(p[i]);
    *(int4*)&txb[(size_t)node * 32 + c] = o.v;
}

// ---------------- propagation (chunk-major, U=4, slim 4B edges) ----------------
// txb layout: [3*NC][N][32] bf16. PASS 1: slice1 = P slice0 ; PASS 2: slice2 = P slice1.
// Block (nodeblock = bid>>LC, chunk = bid&(NC-1)); bid%NC <-> XCD affinity keeps each
// XCD's gather region one 3.2MB chunk table (L2-resident). w = -dinv[s]*dinv[d]
// recomputed per edge (dinv 200KB L2-resident; dinv_d hoisted per node) — bit-identical
// to the stored-weight form.
template <int F, int PASS>
__global__ __launch_bounds__(256) void prop_kernel(ushort_t* __restrict__ txb,
                                                   const int* __restrict__ row_ptr,
                                                   const int* __restrict__ esrc,
                                                   const float* __restrict__ dinv, int N) {
    constexpr int U = 4;
    constexpr int NC = F / 32;                       // chunks (1, 4, 8)
    constexpr int LC = (NC == 1 ? 0 : (NC == 4 ? 2 : 3));
    constexpr int SRCS = (PASS == 1) ? 0 : 1;
    constexpr int DSTS = (PASS == 1) ? 1 : 2;
    int chunk = blockIdx.x & (NC - 1);
    int node = ((blockIdx.x >> LC) << 6) + (threadIdx.x >> 2);
    if (node >= N) return;
    int jo = (threadIdx.x & 3) * 8;
    const ushort_t* srcT = txb + ((size_t)(SRCS * NC + chunk) * N) * 32 + jo;
    ushort_t*       dstT = txb + ((size_t)(DSTS * NC + chunk) * N) * 32 + jo;
    int e0 = row_ptr[node], e1 = row_ptr[node + 1];
    float acc[8] = {};
    int deg = e1 - e0;
    if (deg > 0) {
        float ndinv_d = -dinv[node];                 // hoisted; w = dinv[s] * ndinv_d
        int nbatch = (deg + U - 1) / U;
        int sC[U], sN[U];
        float wC[U], wN[U];
        auto ldE = [&](int ei, int& s_out, float& w_out) {
            int s2 = esrc[ei < e1 ? ei : e1 - 1];
            s_out = s2;
            w_out = (ei < e1) ? dinv[s2] * ndinv_d : 0.f;
        };
#pragma unroll
        for (int j = 0; j < U; ++j) ldE(e0 + j, sC[j], wC[j]);
        for (int b = 0; b < nbatch; ++b) {
            U8 x[U];
#pragma unroll
            for (int j = 0; j < U; ++j)
                x[j].v = *(const int4*)&srcT[(size_t)sC[j] * 32];
            if (b + 1 < nbatch) {
                int nbase = e0 + (b + 1) * U;
#pragma unroll
                for (int j = 0; j < U; ++j) ldE(nbase + j, sN[j], wN[j]);
            }
#pragma unroll
            for (int j = 0; j < U; ++j)
#pragma unroll
                for (int i = 0; i < 8; ++i) acc[i] += wC[j] * bf2f(x[j].u[i]);
#pragma unroll
            for (int j = 0; j < U; ++j) { sC[j] = sN[j]; wC[j] = wN[j]; }
        }
    }
    U8 o;
#pragma unroll
    for (int i = 0; i < 8; ++i) o.u[i] = f2bf(acc[i]);
    *(int4*)&dstT[(size_t)node * 32] = o.v;
}

// Fused folded-weight conversion for all 3 layers (upfront, depends only on W inputs).
// W [3F x Nout] f32 -> Wt [Nout x 3F] bf16, rows [0,F): W0-W2 ; [F,2F): W1 ;
// [2F,3F): 2*W2 (fold exact in f32).
__global__ void convw_all_kernel(const float* __restrict__ W1, const float* __restrict__ W2,
                                 const float* __restrict__ W3, ushort_t* __restrict__ Wt1,
                                 ushort_t* __restrict__ Wt2, ushort_t* __restrict__ Wt3) {
    int id = blockIdx.x * blockDim.x + threadIdx.x;
    const float* W; ushort_t* Wt; int F, Nout, lid;
    if (id < 12288)        { W = W1; Wt = Wt1; F = 32;  Nout = 128; lid = id; }
    else if (id < 110592)  { W = W2; Wt = Wt2; F = 128; Nout = 256; lid = id - 12288; }
    else if (id < 503808)  { W = W3; Wt = Wt3; F = 256; Nout = 512; lid = id - 110592; }
    else return;
    int K = 3 * F;
    int n = lid / K, k = lid % K;
    float val;
    if (k < F)            val = W[(size_t)k * Nout + n] - W[(size_t)(2 * F + k) * Nout + n];
    else if (k < 2 * F)   val = W[(size_t)k * Nout + n];
    else                  val = 2.0f * W[(size_t)k * Nout + n];
    Wt[lid] = f2bf(val);
}

// ---------------- bf16 MFMA GEMM: out = relu(A @ B + bias) ----------------
// A chunk-major [K/32][M][32] bf16 (elem = kt*M + row*32 + j), Bt row-major [Nout][K].
// 128x128 tile, BK=32, double-buffered counted-vmcnt pipeline (vmcnt(4)). XOR-swizzled
// 16B slots via pre-swizzled global source; chunked bijective XCD swizzle. [R10 best]
template <bool BF16OUT, int NY>
__global__ __launch_bounds__(256, 4) void gemm_kernel(const ushort_t* __restrict__ A,
                                                      const ushort_t* __restrict__ Bt,
                                                      const float* __restrict__ bias,
                                                      void* __restrict__ outp,
                                                      int M, int K, int Nout, int nwg) {
    __shared__ ushort_t As[2][128 * 32];
    __shared__ ushort_t Bs[2][128 * 32];
    int tid = threadIdx.x;
    int orig = blockIdx.x;
    int q = nwg >> 3, r = nwg & 7;
    int xcd = orig & 7, m8 = orig >> 3;
    int t = (xcd < r ? xcd * (q + 1) : r * (q + 1) + (xcd - r) * q) + m8;
    int brow = (t / NY) * 128;
    int bcol = (t % NY) * 128;

    int lane = tid & 63, w = tid >> 6;
    int wr = w >> 1, wc = w & 1;
    int g = lane >> 4, lr = lane & 15;
    f32x4 acc[4][4] = {};

    int srow[2], scol[2];
#pragma unroll
    for (int p = 0; p < 2; ++p) {
        int row = (p * 4 + w) * 16 + (lane >> 2);
        srow[p] = row;
        scol[p] = ((lane & 3) ^ ((row >> 1) & 3)) * 8;
    }

    size_t abase[2], bbase[2];
#pragma unroll
    for (int p = 0; p < 2; ++p) {
        int ar = brow + srow[p]; ar = ar < M ? ar : M - 1;
        abase[p] = (size_t)ar * 32 + scol[p];                    // + kt*M per iter
        bbase[p] = (size_t)(bcol + srow[p]) * K + scol[p];       // + kt per iter
    }

    auto stage = [&](int buf, int kt) {
        size_t ka = (size_t)kt * M;
#pragma unroll
        for (int p = 0; p < 2; ++p) {
            gload16(&A[ka + abase[p]], &As[buf][(p * 4 + w) * 512]);
            gload16(&Bt[bbase[p] + kt], &Bs[buf][(p * 4 + w) * 512]);
        }
    };

    int aoff[4], boff4[4];
#pragma unroll
    for (int m = 0; m < 4; ++m) {
        int row = wr * 64 + m * 16 + lr;
        aoff[m] = row * 32 + ((g ^ ((row >> 1) & 3)) * 8);
    }
#pragma unroll
    for (int n = 0; n < 4; ++n) {
        int row = wc * 64 + n * 16 + lr;
        boff4[n] = row * 32 + ((g ^ ((row >> 1) & 3)) * 8);
    }

    stage(0, 0);  // 4 loads -> buf0
    int cur = 0;
    for (int kt = 0; kt < K; kt += 32) {
        if (kt + 32 < K) {
            stage(cur ^ 1, kt + 32);  // 4 more loads in flight -> buf^1
            asm volatile("s_waitcnt vmcnt(4)" ::: "memory");  // cur's 4 landed; prefetch flies
        } else {
            asm volatile("s_waitcnt vmcnt(0)" ::: "memory");  // last tile: drain all
        }
        __builtin_amdgcn_s_barrier();  // all waves' cur-buf loads landed
        bf16x8 a[4], b[4];
#pragma unroll
        for (int m = 0; m < 4; ++m) a[m] = *(const bf16x8*)&As[cur][aoff[m]];
#pragma unroll
        for (int n = 0; n < 4; ++n) b[n] = *(const bf16x8*)&Bs[cur][boff4[n]];
#pragma unroll
        for (int m = 0; m < 4; ++m)
#pragma unroll
            for (int n = 0; n < 4; ++n)
                acc[m][n] = __builtin_amdgcn_mfma_f32_16x16x32_bf16(a[m], b[n], acc[m][n], 0, 0, 0);
        __builtin_amdgcn_s_barrier();  // everyone done reading cur -> next iter may stage it
        cur ^= 1;
    }

#pragma unroll
    for (int m = 0; m < 4; ++m) {
        int grow_base = brow + wr * 64 + m * 16 + g * 4;
#pragma unroll
        for (int n = 0; n < 4; ++n) {
            int gcol = bcol + wc * 64 + n * 16 + lr;
            float bv = bias[gcol];
#pragma unroll
            for (int r2 = 0; r2 < 4; ++r2) {
                int grow = grow_base + r2;
                if (grow < M) {
                    float v2 = acc[m][n][r2] + bv;
                    v2 = v2 > 0.f ? v2 : 0.f;
                    if (BF16OUT)  // chunk-major [Nout/32][M][32]
                        ((ushort_t*)outp)[((size_t)(gcol >> 5) * M + grow) * 32 + (gcol & 31)] = f2bf(v2);
                    else
                        ((float*)outp)[(size_t)grow * Nout + gcol] = v2;
                }
            }
        }
    }
}

extern "C" void kernel_launch(void* const* d_in, const int* in_sizes, int n_in,
                              void* d_out, int out_size, void* d_ws, size_t ws_size,
                              hipStream_t stream) {
    const float* v  = (const float*)d_in[0];
    const int*   ei = (const int*)d_in[1];
    const float* W1 = (const float*)d_in[2];
    const float* b1 = (const float*)d_in[3];
    const float* W2 = (const float*)d_in[4];
    const float* b2 = (const float*)d_in[5];
    const float* W3 = (const float*)d_in[6];
    const float* b3 = (const float*)d_in[7];

    const int N = in_sizes[0] / 32;
    const int E = in_sizes[1] / 2;
    const int* src = ei;
    const int* dst = ei + E;

    char* ws = (char*)d_ws;
    size_t off = 0;
    auto alloc = [&](size_t bytes) {
        off = (off + 255) & ~(size_t)255;
        char* p = ws + off;
        off += bytes;
        return p;
    };
    int*      esrc    = (int*)alloc((size_t)E * 4);
    int*      row_ptr = (int*)alloc((size_t)(N + 1) * 4);
    int*      wofs    = (int*)alloc((size_t)N * 4);
    int*      cnt_src = (int*)alloc((size_t)N * 4);
    int*      cnt_dst = (int*)alloc((size_t)N * 4);
    float*    dinv    = (float*)alloc((size_t)N * 4);
    int*      bsum    = (int*)alloc((size_t)256 * 4);
    int*      boff    = (int*)alloc((size_t)256 * 4);
    ushort_t* WtAll   = (ushort_t*)alloc((size_t)503808 * 2);   // Wt1|Wt2|Wt3
    ushort_t* Wt1     = WtAll;
    ushort_t* Wt2     = WtAll + 12288;
    ushort_t* Wt3     = WtAll + 110592;
    ushort_t* txb3    = (ushort_t*)alloc((size_t)N * 768 * 2);  // [24][N][32] bf16, 76.8MB
    ushort_t* txb1    = txb3;               // [3][N][32] aliases txb3 (dead before gemm2)
    ushort_t* txb2    = (ushort_t*)d_out;   // [12][N][32] in d_out; dead before gemm3 writes
    float*    outF    = (float*)d_out;

    const int nb = (N + 255) / 256;
    const int nbk = (N + 63) / 64;   // prop node-blocks (782)

    // ---- graph build ----
    hipMemsetAsync(cnt_src, 0, (size_t)N * 4, stream);
    hipMemsetAsync(cnt_dst, 0, (size_t)N * 4, stream);
    count_kernel<<<(E + 255) / 256, 256, 0, stream>>>(src, dst, cnt_src, cnt_dst, E, N);
    blocksum_kernel<<<nb, 256, 0, stream>>>(cnt_dst, bsum, N);
    scanblock_kernel<<<1, 256, 0, stream>>>(bsum, boff, nb);
    scatter_scan_kernel<<<nb, 256, 0, stream>>>(cnt_dst, boff, cnt_src, dinv, row_ptr, wofs, N);
    fill_kernel<<<(E + 255) / 256, 256, 0, stream>>>(src, dst, wofs, esrc, E, N);
    convw_all_kernel<<<(503808 + 255) / 256, 256, 0, stream>>>(W1, W2, W3, Wt1, Wt2, Wt3);

    const int mt = (N + 127) / 128;  // 391 row panels

    // ---- layer 1: 32 -> 128 ----  (NC=1)
    convin_kernel<<<(N * 4 + 255) / 256, 256, 0, stream>>>(v, txb1, N);
    prop_kernel<32, 1><<<nbk * 1, 256, 0, stream>>>(txb1, row_ptr, esrc, dinv, N);
    prop_kernel<32, 2><<<nbk * 1, 256, 0, stream>>>(txb1, row_ptr, esrc, dinv, N);
    gemm_kernel<true, 1><<<mt * 1, 256, 0, stream>>>(txb1, Wt1, b1, txb2, N, 96, 128, mt * 1);

    // ---- layer 2: 128 -> 256 ----  (NC=4)
    prop_kernel<128, 1><<<nbk * 4, 256, 0, stream>>>(txb2, row_ptr, esrc, dinv, N);
    prop_kernel<128, 2><<<nbk * 4, 256, 0, stream>>>(txb2, row_ptr, esrc, dinv, N);
    gemm_kernel<true, 2><<<mt * 2, 256, 0, stream>>>(txb2, Wt2, b2, txb3, N, 384, 256, mt * 2);

    // ---- layer 3: 256 -> 512 ----  (NC=8)
    prop_kernel<256, 1><<<nbk * 8, 256, 0, stream>>>(txb3, row_ptr, esrc, dinv, N);
    prop_kernel<256, 2><<<nbk * 8, 256, 0, stream>>>(txb3, row_ptr, esrc, dinv, N);
    gemm_kernel<false, 4><<<mt * 4, 256, 0, stream>>>(txb3, Wt3, b3, outF, N, 768, 512, mt * 4);
}

// Round 20
// 434.198 us; speedup vs baseline: 1.2555x; 1.2555x over previous
//
#include <hip/hip_runtime.h>
#include <hip/hip_bf16.h>

// SpectralMoleculeEncoder: 3-layer ChebConv (K=3), N=50000, E=800000, 32->128->256->512.
// R20 = exact revert to R18 (best verified: 430.5us, absmax 0.03125).
// R19's slim-edge (esrc + recomputed w) REGRESSED to 545us: it inserted a dependent
// random dinv[s] gather per edge (serial L2-latency hop) and doubled the random-request
// count on the request-throughput-limited L2 path. Stored 8B EdgeRec restored.
// Structure: chunk-major bf16 pipeline [3*NC][N][32] with bid%NC<->XCD affinity props
// (U=4 masked batch + EdgeRec prefetch); GEMM 128x128 BK=32 2-buf counted-vmcnt(4),
// XOR-swizzled 16B slots via pre-swizzled global source, bijective XCD swizzle;
// fused convw_all + dinv-in-scatter_scan; hierarchical scan graph build.

typedef __bf16 bf16x8 __attribute__((ext_vector_type(8)));
typedef float f32x4 __attribute__((ext_vector_type(4)));
typedef unsigned short ushort_t;

struct EdgeRec { int s; float w; };

__device__ inline float bf2f(ushort_t u) { return __builtin_bit_cast(float, (unsigned)u << 16); }
__device__ inline ushort_t f2bf(float f) { return __builtin_bit_cast(ushort_t, (__bf16)f); }

union U8 { int4 v; ushort_t u[8]; };

__device__ inline void gload16(const ushort_t* g, ushort_t* l) {
    __builtin_amdgcn_global_load_lds(
        (const __attribute__((address_space(1))) unsigned int*)g,
        (__attribute__((address_space(3))) unsigned int*)l, 16, 0, 0);
}

// ---------------- graph build ----------------
__global__ void count_kernel(const int* __restrict__ src, const int* __restrict__ dst,
                             int* __restrict__ cnt_src, int* __restrict__ cnt_dst, int E, int N) {
    int e = blockIdx.x * blockDim.x + threadIdx.x;
    if (e >= E) return;
    int s = src[e], d = dst[e];
    if ((unsigned)s < (unsigned)N) atomicAdd(&cnt_src[s], 1);
    if ((unsigned)d < (unsigned)N) atomicAdd(&cnt_dst[d], 1);
}

// ---- hierarchical exclusive scan of cnt[N] -> row_ptr[N+1], wofs[N] ----
__global__ void blocksum_kernel(const int* __restrict__ cnt, int* __restrict__ bsum, int N) {
    int i = blockIdx.x * 256 + threadIdx.x;
    int v = (i < N) ? cnt[i] : 0;
#pragma unroll
    for (int off = 32; off >= 1; off >>= 1) v += __shfl_xor(v, off);
    __shared__ int ws[4];
    if ((threadIdx.x & 63) == 0) ws[threadIdx.x >> 6] = v;
    __syncthreads();
    if (threadIdx.x == 0) bsum[blockIdx.x] = ws[0] + ws[1] + ws[2] + ws[3];
}

__global__ void scanblock_kernel(const int* __restrict__ arr, int* __restrict__ out, int nb) {
    __shared__ int s[256];
    int t = threadIdx.x;
    int v = (t < nb) ? arr[t] : 0;
    s[t] = v;
    __syncthreads();
#pragma unroll
    for (int off = 1; off < 256; off <<= 1) {
        int u = (t >= off) ? s[t - off] : 0;
        __syncthreads();
        s[t] += u;
        __syncthreads();
    }
    if (t < nb) out[t] = s[t] - v;  // exclusive
}

// fused: scan-scatter for row_ptr/wofs + dinv (from cnt_src)
__global__ void scatter_scan_kernel(const int* __restrict__ cnt, const int* __restrict__ boff,
                                    const int* __restrict__ cnt_src, float* __restrict__ dinv,
                                    int* __restrict__ row_ptr, int* __restrict__ wofs, int N) {
    __shared__ int s[256];
    int t = threadIdx.x;
    int i = blockIdx.x * 256 + t;
    int v = (i < N) ? cnt[i] : 0;
    s[t] = v;
    __syncthreads();
#pragma unroll
    for (int off = 1; off < 256; off <<= 1) {
        int u = (t >= off) ? s[t - off] : 0;
        __syncthreads();
        s[t] += u;
        __syncthreads();
    }
    int run = boff[blockIdx.x] + s[t] - v;
    if (i < N) {
        row_ptr[i] = run; wofs[i] = run;
        int c = cnt_src[i];
        dinv[i] = (c > 0) ? rsqrtf((float)c) : 0.0f;
    } else if (i == N) row_ptr[N] = run;
}

__global__ void fill_kernel(const int* __restrict__ src, const int* __restrict__ dst,
                            const float* __restrict__ dinv, int* __restrict__ wofs,
                            EdgeRec* __restrict__ ep, int E, int N) {
    int e = blockIdx.x * blockDim.x + threadIdx.x;
    if (e >= E) return;
    int s = src[e], d = dst[e];
    if ((unsigned)s >= (unsigned)N || (unsigned)d >= (unsigned)N) return;
    int pos = atomicAdd(&wofs[d], 1);
    EdgeRec er; er.s = s; er.w = -dinv[s] * dinv[d];
    ep[pos] = er;
}

// v [N,32] f32 -> txb1 slice0 (chunk-major, NC=1 == [N][32]) bf16
__global__ void convin_kernel(const float* __restrict__ v, ushort_t* __restrict__ txb, int N) {
    int id = blockIdx.x * blockDim.x + threadIdx.x;
    if (id >= N * 4) return;
    int node = id >> 2, c = (id & 3) << 3;
    const float* p = &v[(size_t)node * 32 + c];
    U8 o;
#pragma unroll
    for (int i = 0; i < 8; ++i) o.u[i] = f2bf(p[i]);
    *(int4*)&txb[(size_t)node * 32 + c] = o.v;
}

// ---------------- propagation (chunk-major, U=4 — R10/R18 form) ----------------
// txb layout: [3*NC][N][32] bf16. PASS 1: slice1 = P slice0 ; PASS 2: slice2 = P slice1.
// Block (nodeblock = bid>>LC, chunk = bid&(NC-1)); bid%NC <-> XCD affinity keeps each
// XCD's gather region one 3.2MB chunk table (L2-resident).
template <int F, int PASS>
__global__ __launch_bounds__(256) void prop_kernel(ushort_t* __restrict__ txb,
                                                   const int* __restrict__ row_ptr,
                                                   const EdgeRec* __restrict__ ep, int N) {
    constexpr int U = 4;
    constexpr int NC = F / 32;                       // chunks (1, 4, 8)
    constexpr int LC = (NC == 1 ? 0 : (NC == 4 ? 2 : 3));
    constexpr int SRCS = (PASS == 1) ? 0 : 1;
    constexpr int DSTS = (PASS == 1) ? 1 : 2;
    int chunk = blockIdx.x & (NC - 1);
    int node = ((blockIdx.x >> LC) << 6) + (threadIdx.x >> 2);
    if (node >= N) return;
    int jo = (threadIdx.x & 3) * 8;
    const ushort_t* srcT = txb + ((size_t)(SRCS * NC + chunk) * N) * 32 + jo;
    ushort_t*       dstT = txb + ((size_t)(DSTS * NC + chunk) * N) * 32 + jo;
    int e0 = row_ptr[node], e1 = row_ptr[node + 1];
    float acc[8] = {};
    int deg = e1 - e0;
    if (deg > 0) {
        int nbatch = (deg + U - 1) / U;
        EdgeRec cur[U], nxt[U];
#pragma unroll
        for (int j = 0; j < U; ++j) {
            int ei = e0 + j;
            EdgeRec rr = ep[ei < e1 ? ei : e1 - 1];
            if (ei >= e1) rr.w = 0.f;
            cur[j] = rr;
        }
        for (int b = 0; b < nbatch; ++b) {
            U8 x[U];
#pragma unroll
            for (int j = 0; j < U; ++j)
                x[j].v = *(const int4*)&srcT[(size_t)cur[j].s * 32];
            if (b + 1 < nbatch) {
                int nbase = e0 + (b + 1) * U;
#pragma unroll
                for (int j = 0; j < U; ++j) {
                    int ei = nbase + j;
                    EdgeRec rr = ep[ei < e1 ? ei : e1 - 1];
                    if (ei >= e1) rr.w = 0.f;
                    nxt[j] = rr;
                }
            }
#pragma unroll
            for (int j = 0; j < U; ++j)
#pragma unroll
                for (int i = 0; i < 8; ++i) acc[i] += cur[j].w * bf2f(x[j].u[i]);
#pragma unroll
            for (int j = 0; j < U; ++j) cur[j] = nxt[j];
        }
    }
    U8 o;
#pragma unroll
    for (int i = 0; i < 8; ++i) o.u[i] = f2bf(acc[i]);
    *(int4*)&dstT[(size_t)node * 32] = o.v;
}

// Fused folded-weight conversion for all 3 layers (upfront, depends only on W inputs).
// W [3F x Nout] f32 -> Wt [Nout x 3F] bf16, rows [0,F): W0-W2 ; [F,2F): W1 ;
// [2F,3F): 2*W2 (fold exact in f32).
__global__ void convw_all_kernel(const float* __restrict__ W1, const float* __restrict__ W2,
                                 const float* __restrict__ W3, ushort_t* __restrict__ Wt1,
                                 ushort_t* __restrict__ Wt2, ushort_t* __restrict__ Wt3) {
    int id = blockIdx.x * blockDim.x + threadIdx.x;
    const float* W; ushort_t* Wt; int F, Nout, lid;
    if (id < 12288)        { W = W1; Wt = Wt1; F = 32;  Nout = 128; lid = id; }
    else if (id < 110592)  { W = W2; Wt = Wt2; F = 128; Nout = 256; lid = id - 12288; }
    else if (id < 503808)  { W = W3; Wt = Wt3; F = 256; Nout = 512; lid = id - 110592; }
    else return;
    int K = 3 * F;
    int n = lid / K, k = lid % K;
    float val;
    if (k < F)            val = W[(size_t)k * Nout + n] - W[(size_t)(2 * F + k) * Nout + n];
    else if (k < 2 * F)   val = W[(size_t)k * Nout + n];
    else                  val = 2.0f * W[(size_t)k * Nout + n];
    Wt[lid] = f2bf(val);
}

// ---------------- bf16 MFMA GEMM: out = relu(A @ B + bias) ----------------
// A chunk-major [K/32][M][32] bf16 (elem = kt*M + row*32 + j), Bt row-major [Nout][K].
// 128x128 tile, BK=32, double-buffered counted-vmcnt pipeline (vmcnt(4)). XOR-swizzled
// 16B slots via pre-swizzled global source; chunked bijective XCD swizzle. [R10 best]
template <bool BF16OUT, int NY>
__global__ __launch_bounds__(256, 4) void gemm_kernel(const ushort_t* __restrict__ A,
                                                      const ushort_t* __restrict__ Bt,
                                                      const float* __restrict__ bias,
                                                      void* __restrict__ outp,
                                                      int M, int K, int Nout, int nwg) {
    __shared__ ushort_t As[2][128 * 32];
    __shared__ ushort_t Bs[2][128 * 32];
    int tid = threadIdx.x;
    int orig = blockIdx.x;
    int q = nwg >> 3, r = nwg & 7;
    int xcd = orig & 7, m8 = orig >> 3;
    int t = (xcd < r ? xcd * (q + 1) : r * (q + 1) + (xcd - r) * q) + m8;
    int brow = (t / NY) * 128;
    int bcol = (t % NY) * 128;

    int lane = tid & 63, w = tid >> 6;
    int wr = w >> 1, wc = w & 1;
    int g = lane >> 4, lr = lane & 15;
    f32x4 acc[4][4] = {};

    int srow[2], scol[2];
#pragma unroll
    for (int p = 0; p < 2; ++p) {
        int row = (p * 4 + w) * 16 + (lane >> 2);
        srow[p] = row;
        scol[p] = ((lane & 3) ^ ((row >> 1) & 3)) * 8;
    }

    size_t abase[2], bbase[2];
#pragma unroll
    for (int p = 0; p < 2; ++p) {
        int ar = brow + srow[p]; ar = ar < M ? ar : M - 1;
        abase[p] = (size_t)ar * 32 + scol[p];                    // + kt*M per iter
        bbase[p] = (size_t)(bcol + srow[p]) * K + scol[p];       // + kt per iter
    }

    auto stage = [&](int buf, int kt) {
        size_t ka = (size_t)kt * M;
#pragma unroll
        for (int p = 0; p < 2; ++p) {
            gload16(&A[ka + abase[p]], &As[buf][(p * 4 + w) * 512]);
            gload16(&Bt[bbase[p] + kt], &Bs[buf][(p * 4 + w) * 512]);
        }
    };

    int aoff[4], boff4[4];
#pragma unroll
    for (int m = 0; m < 4; ++m) {
        int row = wr * 64 + m * 16 + lr;
        aoff[m] = row * 32 + ((g ^ ((row >> 1) & 3)) * 8);
    }
#pragma unroll
    for (int n = 0; n < 4; ++n) {
        int row = wc * 64 + n * 16 + lr;
        boff4[n] = row * 32 + ((g ^ ((row >> 1) & 3)) * 8);
    }

    stage(0, 0);  // 4 loads -> buf0
    int cur = 0;
    for (int kt = 0; kt < K; kt += 32) {
        if (kt + 32 < K) {
            stage(cur ^ 1, kt + 32);  // 4 more loads in flight -> buf^1
            asm volatile("s_waitcnt vmcnt(4)" ::: "memory");  // cur's 4 landed; prefetch flies
        } else {
            asm volatile("s_waitcnt vmcnt(0)" ::: "memory");  // last tile: drain all
        }
        __builtin_amdgcn_s_barrier();  // all waves' cur-buf loads landed
        bf16x8 a[4], b[4];
#pragma unroll
        for (int m = 0; m < 4; ++m) a[m] = *(const bf16x8*)&As[cur][aoff[m]];
#pragma unroll
        for (int n = 0; n < 4; ++n) b[n] = *(const bf16x8*)&Bs[cur][boff4[n]];
#pragma unroll
        for (int m = 0; m < 4; ++m)
#pragma unroll
            for (int n = 0; n < 4; ++n)
                acc[m][n] = __builtin_amdgcn_mfma_f32_16x16x32_bf16(a[m], b[n], acc[m][n], 0, 0, 0);
        __builtin_amdgcn_s_barrier();  // everyone done reading cur -> next iter may stage it
        cur ^= 1;
    }

#pragma unroll
    for (int m = 0; m < 4; ++m) {
        int grow_base = brow + wr * 64 + m * 16 + g * 4;
#pragma unroll
        for (int n = 0; n < 4; ++n) {
            int gcol = bcol + wc * 64 + n * 16 + lr;
            float bv = bias[gcol];
#pragma unroll
            for (int r2 = 0; r2 < 4; ++r2) {
                int grow = grow_base + r2;
                if (grow < M) {
                    float v2 = acc[m][n][r2] + bv;
                    v2 = v2 > 0.f ? v2 : 0.f;
                    if (BF16OUT)  // chunk-major [Nout/32][M][32]
                        ((ushort_t*)outp)[((size_t)(gcol >> 5) * M + grow) * 32 + (gcol & 31)] = f2bf(v2);
                    else
                        ((float*)outp)[(size_t)grow * Nout + gcol] = v2;
                }
            }
        }
    }
}

extern "C" void kernel_launch(void* const* d_in, const int* in_sizes, int n_in,
                              void* d_out, int out_size, void* d_ws, size_t ws_size,
                              hipStream_t stream) {
    const float* v  = (const float*)d_in[0];
    const int*   ei = (const int*)d_in[1];
    const float* W1 = (const float*)d_in[2];
    const float* b1 = (const float*)d_in[3];
    const float* W2 = (const float*)d_in[4];
    const float* b2 = (const float*)d_in[5];
    const float* W3 = (const float*)d_in[6];
    const float* b3 = (const float*)d_in[7];

    const int N = in_sizes[0] / 32;
    const int E = in_sizes[1] / 2;
    const int* src = ei;
    const int* dst = ei + E;

    char* ws = (char*)d_ws;
    size_t off = 0;
    auto alloc = [&](size_t bytes) {
        off = (off + 255) & ~(size_t)255;
        char* p = ws + off;
        off += bytes;
        return p;
    };
    EdgeRec*  ep      = (EdgeRec*)alloc((size_t)E * 8);
    int*      row_ptr = (int*)alloc((size_t)(N + 1) * 4);
    int*      wofs    = (int*)alloc((size_t)N * 4);
    int*      cnt_src = (int*)alloc((size_t)N * 4);
    int*      cnt_dst = (int*)alloc((size_t)N * 4);
    float*    dinv    = (float*)alloc((size_t)N * 4);
    int*      bsum    = (int*)alloc((size_t)256 * 4);
    int*      boff    = (int*)alloc((size_t)256 * 4);
    ushort_t* WtAll   = (ushort_t*)alloc((size_t)503808 * 2);   // Wt1|Wt2|Wt3
    ushort_t* Wt1     = WtAll;
    ushort_t* Wt2     = WtAll + 12288;
    ushort_t* Wt3     = WtAll + 110592;
    ushort_t* txb3    = (ushort_t*)alloc((size_t)N * 768 * 2);  // [24][N][32] bf16, 76.8MB
    ushort_t* txb1    = txb3;               // [3][N][32] aliases txb3 (dead before gemm2)
    ushort_t* txb2    = (ushort_t*)d_out;   // [12][N][32] in d_out; dead before gemm3 writes
    float*    outF    = (float*)d_out;

    const int nb = (N + 255) / 256;
    const int nbk = (N + 63) / 64;   // prop node-blocks (782)

    // ---- graph build ----
    hipMemsetAsync(cnt_src, 0, (size_t)N * 4, stream);
    hipMemsetAsync(cnt_dst, 0, (size_t)N * 4, stream);
    count_kernel<<<(E + 255) / 256, 256, 0, stream>>>(src, dst, cnt_src, cnt_dst, E, N);
    blocksum_kernel<<<nb, 256, 0, stream>>>(cnt_dst, bsum, N);
    scanblock_kernel<<<1, 256, 0, stream>>>(bsum, boff, nb);
    scatter_scan_kernel<<<nb, 256, 0, stream>>>(cnt_dst, boff, cnt_src, dinv, row_ptr, wofs, N);
    fill_kernel<<<(E + 255) / 256, 256, 0, stream>>>(src, dst, dinv, wofs, ep, E, N);
    convw_all_kernel<<<(503808 + 255) / 256, 256, 0, stream>>>(W1, W2, W3, Wt1, Wt2, Wt3);

    const int mt = (N + 127) / 128;  // 391 row panels

    // ---- layer 1: 32 -> 128 ----  (NC=1)
    convin_kernel<<<(N * 4 + 255) / 256, 256, 0, stream>>>(v, txb1, N);
    prop_kernel<32, 1><<<nbk * 1, 256, 0, stream>>>(txb1, row_ptr, ep, N);
    prop_kernel<32, 2><<<nbk * 1, 256, 0, stream>>>(txb1, row_ptr, ep, N);
    gemm_kernel<true, 1><<<mt * 1, 256, 0, stream>>>(txb1, Wt1, b1, txb2, N, 96, 128, mt * 1);

    // ---- layer 2: 128 -> 256 ----  (NC=4)
    prop_kernel<128, 1><<<nbk * 4, 256, 0, stream>>>(txb2, row_ptr, ep, N);
    prop_kernel<128, 2><<<nbk * 4, 256, 0, stream>>>(txb2, row_ptr, ep, N);
    gemm_kernel<true, 2><<<mt * 2, 256, 0, stream>>>(txb2, Wt2, b2, txb3, N, 384, 256, mt * 2);

    // ---- layer 3: 256 -> 512 ----  (NC=8)
    prop_kernel<256, 1><<<nbk * 8, 256, 0, stream>>>(txb3, row_ptr, ep, N);
    prop_kernel<256, 2><<<nbk * 8, 256, 0, stream>>>(txb3, row_ptr, ep, N);
    gemm_kernel<false, 4><<<mt * 4, 256, 0, stream>>>(txb3, Wt3, b3, outF, N, 768, 512, mt * 4);
}

// Round 21
// 430.173 us; speedup vs baseline: 1.2673x; 1.0094x over previous
//
#include <hip/hip_runtime.h>
#include <hip/hip_bf16.h>

// SpectralMoleculeEncoder: 3-layer ChebConv (K=3), N=50000, E=800000, 32->128->256->512.
// R21 = R20 with GEMM retiled 128x128/4-wave -> 256x128/8-wave (512 thr), SAME 2-barrier
// counted-vmcnt skeleton (vmcnt(3): 3 loads/thread/iter = 2xA + 1xB). Loads-per-MFMA
// -25%, barrier cost per output halved, B-panel reuse x2. LDS 48KB (3 blocks/CU cap,
// 24 waves/CU). MFMA shape/K-order/acc order unchanged -> bit-identical (canary 0.03125).
// Props/build = R20 exactly (best verified structure).

typedef __bf16 bf16x8 __attribute__((ext_vector_type(8)));
typedef float f32x4 __attribute__((ext_vector_type(4)));
typedef unsigned short ushort_t;

struct EdgeRec { int s; float w; };

__device__ inline float bf2f(ushort_t u) { return __builtin_bit_cast(float, (unsigned)u << 16); }
__device__ inline ushort_t f2bf(float f) { return __builtin_bit_cast(ushort_t, (__bf16)f); }

union U8 { int4 v; ushort_t u[8]; };

__device__ inline void gload16(const ushort_t* g, ushort_t* l) {
    __builtin_amdgcn_global_load_lds(
        (const __attribute__((address_space(1))) unsigned int*)g,
        (__attribute__((address_space(3))) unsigned int*)l, 16, 0, 0);
}

// ---------------- graph build ----------------
__global__ void count_kernel(const int* __restrict__ src, const int* __restrict__ dst,
                             int* __restrict__ cnt_src, int* __restrict__ cnt_dst, int E, int N) {
    int e = blockIdx.x * blockDim.x + threadIdx.x;
    if (e >= E) return;
    int s = src[e], d = dst[e];
    if ((unsigned)s < (unsigned)N) atomicAdd(&cnt_src[s], 1);
    if ((unsigned)d < (unsigned)N) atomicAdd(&cnt_dst[d], 1);
}

// ---- hierarchical exclusive scan of cnt[N] -> row_ptr[N+1], wofs[N] ----
__global__ void blocksum_kernel(const int* __restrict__ cnt, int* __restrict__ bsum, int N) {
    int i = blockIdx.x * 256 + threadIdx.x;
    int v = (i < N) ? cnt[i] : 0;
#pragma unroll
    for (int off = 32; off >= 1; off >>= 1) v += __shfl_xor(v, off);
    __shared__ int ws[4];
    if ((threadIdx.x & 63) == 0) ws[threadIdx.x >> 6] = v;
    __syncthreads();
    if (threadIdx.x == 0) bsum[blockIdx.x] = ws[0] + ws[1] + ws[2] + ws[3];
}

__global__ void scanblock_kernel(const int* __restrict__ arr, int* __restrict__ out, int nb) {
    __shared__ int s[256];
    int t = threadIdx.x;
    int v = (t < nb) ? arr[t] : 0;
    s[t] = v;
    __syncthreads();
#pragma unroll
    for (int off = 1; off < 256; off <<= 1) {
        int u = (t >= off) ? s[t - off] : 0;
        __syncthreads();
        s[t] += u;
        __syncthreads();
    }
    if (t < nb) out[t] = s[t] - v;  // exclusive
}

// fused: scan-scatter for row_ptr/wofs + dinv (from cnt_src)
__global__ void scatter_scan_kernel(const int* __restrict__ cnt, const int* __restrict__ boff,
                                    const int* __restrict__ cnt_src, float* __restrict__ dinv,
                                    int* __restrict__ row_ptr, int* __restrict__ wofs, int N) {
    __shared__ int s[256];
    int t = threadIdx.x;
    int i = blockIdx.x * 256 + t;
    int v = (i < N) ? cnt[i] : 0;
    s[t] = v;
    __syncthreads();
#pragma unroll
    for (int off = 1; off < 256; off <<= 1) {
        int u = (t >= off) ? s[t - off] : 0;
        __syncthreads();
        s[t] += u;
        __syncthreads();
    }
    int run = boff[blockIdx.x] + s[t] - v;
    if (i < N) {
        row_ptr[i] = run; wofs[i] = run;
        int c = cnt_src[i];
        dinv[i] = (c > 0) ? rsqrtf((float)c) : 0.0f;
    } else if (i == N) row_ptr[N] = run;
}

__global__ void fill_kernel(const int* __restrict__ src, const int* __restrict__ dst,
                            const float* __restrict__ dinv, int* __restrict__ wofs,
                            EdgeRec* __restrict__ ep, int E, int N) {
    int e = blockIdx.x * blockDim.x + threadIdx.x;
    if (e >= E) return;
    int s = src[e], d = dst[e];
    if ((unsigned)s >= (unsigned)N || (unsigned)d >= (unsigned)N) return;
    int pos = atomicAdd(&wofs[d], 1);
    EdgeRec er; er.s = s; er.w = -dinv[s] * dinv[d];
    ep[pos] = er;
}

// v [N,32] f32 -> txb1 slice0 (chunk-major, NC=1 == [N][32]) bf16
__global__ void convin_kernel(const float* __restrict__ v, ushort_t* __restrict__ txb, int N) {
    int id = blockIdx.x * blockDim.x + threadIdx.x;
    if (id >= N * 4) return;
    int node = id >> 2, c = (id & 3) << 3;
    const float* p = &v[(size_t)node * 32 + c];
    U8 o;
#pragma unroll
    for (int i = 0; i < 8; ++i) o.u[i] = f2bf(p[i]);
    *(int4*)&txb[(size_t)node * 32 + c] = o.v;
}

// ---------------- propagation (chunk-major, U=4 — R10/R18 form) ----------------
template <int F, int PASS>
__global__ __launch_bounds__(256) void prop_kernel(ushort_t* __restrict__ txb,
                                                   const int* __restrict__ row_ptr,
                                                   const EdgeRec* __restrict__ ep, int N) {
    constexpr int U = 4;
    constexpr int NC = F / 32;                       // chunks (1, 4, 8)
    constexpr int LC = (NC == 1 ? 0 : (NC == 4 ? 2 : 3));
    constexpr int SRCS = (PASS == 1) ? 0 : 1;
    constexpr int DSTS = (PASS == 1) ? 1 : 2;
    int chunk = blockIdx.x & (NC - 1);
    int node = ((blockIdx.x >> LC) << 6) + (threadIdx.x >> 2);
    if (node >= N) return;
    int jo = (threadIdx.x & 3) * 8;
    const ushort_t* srcT = txb + ((size_t)(SRCS * NC + chunk) * N) * 32 + jo;
    ushort_t*       dstT = txb + ((size_t)(DSTS * NC + chunk) * N) * 32 + jo;
    int e0 = row_ptr[node], e1 = row_ptr[node + 1];
    float acc[8] = {};
    int deg = e1 - e0;
    if (deg > 0) {
        int nbatch = (deg + U - 1) / U;
        EdgeRec cur[U], nxt[U];
#pragma unroll
        for (int j = 0; j < U; ++j) {
            int ei = e0 + j;
            EdgeRec rr = ep[ei < e1 ? ei : e1 - 1];
            if (ei >= e1) rr.w = 0.f;
            cur[j] = rr;
        }
        for (int b = 0; b < nbatch; ++b) {
            U8 x[U];
#pragma unroll
            for (int j = 0; j < U; ++j)
                x[j].v = *(const int4*)&srcT[(size_t)cur[j].s * 32];
            if (b + 1 < nbatch) {
                int nbase = e0 + (b + 1) * U;
#pragma unroll
                for (int j = 0; j < U; ++j) {
                    int ei = nbase + j;
                    EdgeRec rr = ep[ei < e1 ? ei : e1 - 1];
                    if (ei >= e1) rr.w = 0.f;
                    nxt[j] = rr;
                }
            }
#pragma unroll
            for (int j = 0; j < U; ++j)
#pragma unroll
                for (int i = 0; i < 8; ++i) acc[i] += cur[j].w * bf2f(x[j].u[i]);
#pragma unroll
            for (int j = 0; j < U; ++j) cur[j] = nxt[j];
        }
    }
    U8 o;
#pragma unroll
    for (int i = 0; i < 8; ++i) o.u[i] = f2bf(acc[i]);
    *(int4*)&dstT[(size_t)node * 32] = o.v;
}

// Fused folded-weight conversion for all 3 layers.
__global__ void convw_all_kernel(const float* __restrict__ W1, const float* __restrict__ W2,
                                 const float* __restrict__ W3, ushort_t* __restrict__ Wt1,
                                 ushort_t* __restrict__ Wt2, ushort_t* __restrict__ Wt3) {
    int id = blockIdx.x * blockDim.x + threadIdx.x;
    const float* W; ushort_t* Wt; int F, Nout, lid;
    if (id < 12288)        { W = W1; Wt = Wt1; F = 32;  Nout = 128; lid = id; }
    else if (id < 110592)  { W = W2; Wt = Wt2; F = 128; Nout = 256; lid = id - 12288; }
    else if (id < 503808)  { W = W3; Wt = Wt3; F = 256; Nout = 512; lid = id - 110592; }
    else return;
    int K = 3 * F;
    int n = lid / K, k = lid % K;
    float val;
    if (k < F)            val = W[(size_t)k * Nout + n] - W[(size_t)(2 * F + k) * Nout + n];
    else if (k < 2 * F)   val = W[(size_t)k * Nout + n];
    else                  val = 2.0f * W[(size_t)k * Nout + n];
    Wt[lid] = f2bf(val);
}

// ---------------- bf16 MFMA GEMM: out = relu(A @ B + bias) ----------------
// 256x128 tile, 8 waves (4M x 2N, each 64x64), BK=32, 2-barrier counted-vmcnt pipeline
// (3 loads/thread/iter: 2xA + 1xB; vmcnt(3) keeps next tile in flight). A chunk-major
// [K/32][M][32]; Bt row-major [Nout][K]. XOR-swizzled 16B slots via pre-swizzled global
// source; bijective chunked XCD swizzle. LDS 48KB.
template <bool BF16OUT, int NY>
__global__ __launch_bounds__(512) void gemm_kernel(const ushort_t* __restrict__ A,
                                                   const ushort_t* __restrict__ Bt,
                                                   const float* __restrict__ bias,
                                                   void* __restrict__ outp,
                                                   int M, int K, int Nout, int nwg) {
    __shared__ ushort_t As[2][256 * 32];   // 16KB per buf
    __shared__ ushort_t Bs[2][128 * 32];   // 8KB per buf
    int tid = threadIdx.x;
    int orig = blockIdx.x;
    int q = nwg >> 3, r = nwg & 7;
    int xcd = orig & 7, m8 = orig >> 3;
    int t = (xcd < r ? xcd * (q + 1) : r * (q + 1) + (xcd - r) * q) + m8;
    int brow = (t / NY) * 256;
    int bcol = (t % NY) * 128;

    int lane = tid & 63, w = tid >> 6;      // w in [0,8)
    int wr = w >> 1, wc = w & 1;            // 4M x 2N waves
    int g = lane >> 4, lr = lane & 15;
    f32x4 acc[4][4] = {};

    // A staging: chunk (p*8+w) covers rows [(p*8+w)*16, +16), p in {0,1}
    int arow[2], ascol[2];
#pragma unroll
    for (int p = 0; p < 2; ++p) {
        int row = (p * 8 + w) * 16 + (lane >> 2);
        arow[p] = row;
        ascol[p] = ((lane & 3) ^ ((row >> 1) & 3)) * 8;
    }
    // B staging: chunk w covers rows [w*16, +16)
    int brow_s = w * 16 + (lane >> 2);
    int bscol = ((lane & 3) ^ ((brow_s >> 1) & 3)) * 8;

    size_t abase[2], bbase;
#pragma unroll
    for (int p = 0; p < 2; ++p) {
        int ar = brow + arow[p]; ar = ar < M ? ar : M - 1;  // clamp; stores guarded
        abase[p] = (size_t)ar * 32 + ascol[p];              // + kt*M per iter (chunk-major)
    }
    bbase = (size_t)(bcol + brow_s) * K + bscol;            // + kt per iter

    auto stage = [&](int buf, int kt) {
        size_t ka = (size_t)kt * M;
#pragma unroll
        for (int p = 0; p < 2; ++p)
            gload16(&A[ka + abase[p]], &As[buf][(p * 8 + w) * 512]);
        gload16(&Bt[bbase + kt], &Bs[buf][w * 512]);
    };

    int aoff[4], boff4[4];
#pragma unroll
    for (int m = 0; m < 4; ++m) {
        int row = wr * 64 + m * 16 + lr;                    // rows 0..255
        aoff[m] = row * 32 + ((g ^ ((row >> 1) & 3)) * 8);
    }
#pragma unroll
    for (int n = 0; n < 4; ++n) {
        int row = wc * 64 + n * 16 + lr;                    // rows 0..127
        boff4[n] = row * 32 + ((g ^ ((row >> 1) & 3)) * 8);
    }

    stage(0, 0);  // 3 loads -> buf0
    int cur = 0;
    for (int kt = 0; kt < K; kt += 32) {
        if (kt + 32 < K) {
            stage(cur ^ 1, kt + 32);  // 3 more loads in flight -> buf^1
            asm volatile("s_waitcnt vmcnt(3)" ::: "memory");  // cur's 3 landed; prefetch flies
        } else {
            asm volatile("s_waitcnt vmcnt(0)" ::: "memory");  // last tile: drain all
        }
        __builtin_amdgcn_s_barrier();  // all waves' cur-buf loads landed
        bf16x8 a[4], b[4];
#pragma unroll
        for (int m = 0; m < 4; ++m) a[m] = *(const bf16x8*)&As[cur][aoff[m]];
#pragma unroll
        for (int n = 0; n < 4; ++n) b[n] = *(const bf16x8*)&Bs[cur][boff4[n]];
#pragma unroll
        for (int m = 0; m < 4; ++m)
#pragma unroll
            for (int n = 0; n < 4; ++n)
                acc[m][n] = __builtin_amdgcn_mfma_f32_16x16x32_bf16(a[m], b[n], acc[m][n], 0, 0, 0);
        __builtin_amdgcn_s_barrier();  // everyone done reading cur -> next iter may stage it
        cur ^= 1;
    }

#pragma unroll
    for (int m = 0; m < 4; ++m) {
        int grow_base = brow + wr * 64 + m * 16 + g * 4;
#pragma unroll
        for (int n = 0; n < 4; ++n) {
            int gcol = bcol + wc * 64 + n * 16 + lr;
            float bv = bias[gcol];
#pragma unroll
            for (int r2 = 0; r2 < 4; ++r2) {
                int grow = grow_base + r2;
                if (grow < M) {
                    float v2 = acc[m][n][r2] + bv;
                    v2 = v2 > 0.f ? v2 : 0.f;
                    if (BF16OUT)  // chunk-major [Nout/32][M][32]
                        ((ushort_t*)outp)[((size_t)(gcol >> 5) * M + grow) * 32 + (gcol & 31)] = f2bf(v2);
                    else
                        ((float*)outp)[(size_t)grow * Nout + gcol] = v2;
                }
            }
        }
    }
}

extern "C" void kernel_launch(void* const* d_in, const int* in_sizes, int n_in,
                              void* d_out, int out_size, void* d_ws, size_t ws_size,
                              hipStream_t stream) {
    const float* v  = (const float*)d_in[0];
    const int*   ei = (const int*)d_in[1];
    const float* W1 = (const float*)d_in[2];
    const float* b1 = (const float*)d_in[3];
    const float* W2 = (const float*)d_in[4];
    const float* b2 = (const float*)d_in[5];
    const float* W3 = (const float*)d_in[6];
    const float* b3 = (const float*)d_in[7];

    const int N = in_sizes[0] / 32;
    const int E = in_sizes[1] / 2;
    const int* src = ei;
    const int* dst = ei + E;

    char* ws = (char*)d_ws;
    size_t off = 0;
    auto alloc = [&](size_t bytes) {
        off = (off + 255) & ~(size_t)255;
        char* p = ws + off;
        off += bytes;
        return p;
    };
    EdgeRec*  ep      = (EdgeRec*)alloc((size_t)E * 8);
    int*      row_ptr = (int*)alloc((size_t)(N + 1) * 4);
    int*      wofs    = (int*)alloc((size_t)N * 4);
    int*      cnt_src = (int*)alloc((size_t)N * 4);
    int*      cnt_dst = (int*)alloc((size_t)N * 4);
    float*    dinv    = (float*)alloc((size_t)N * 4);
    int*      bsum    = (int*)alloc((size_t)256 * 4);
    int*      boff    = (int*)alloc((size_t)256 * 4);
    ushort_t* WtAll   = (ushort_t*)alloc((size_t)503808 * 2);   // Wt1|Wt2|Wt3
    ushort_t* Wt1     = WtAll;
    ushort_t* Wt2     = WtAll + 12288;
    ushort_t* Wt3     = WtAll + 110592;
    ushort_t* txb3    = (ushort_t*)alloc((size_t)N * 768 * 2);  // [24][N][32] bf16, 76.8MB
    ushort_t* txb1    = txb3;               // [3][N][32] aliases txb3 (dead before gemm2)
    ushort_t* txb2    = (ushort_t*)d_out;   // [12][N][32] in d_out; dead before gemm3 writes
    float*    outF    = (float*)d_out;

    const int nb = (N + 255) / 256;
    const int nbk = (N + 63) / 64;   // prop node-blocks (782)

    // ---- graph build ----
    hipMemsetAsync(cnt_src, 0, (size_t)N * 4, stream);
    hipMemsetAsync(cnt_dst, 0, (size_t)N * 4, stream);
    count_kernel<<<(E + 255) / 256, 256, 0, stream>>>(src, dst, cnt_src, cnt_dst, E, N);
    blocksum_kernel<<<nb, 256, 0, stream>>>(cnt_dst, bsum, N);
    scanblock_kernel<<<1, 256, 0, stream>>>(bsum, boff, nb);
    scatter_scan_kernel<<<nb, 256, 0, stream>>>(cnt_dst, boff, cnt_src, dinv, row_ptr, wofs, N);
    fill_kernel<<<(E + 255) / 256, 256, 0, stream>>>(src, dst, dinv, wofs, ep, E, N);
    convw_all_kernel<<<(503808 + 255) / 256, 256, 0, stream>>>(W1, W2, W3, Wt1, Wt2, Wt3);

    const int mt = (N + 255) / 256;  // 196 row panels (BM=256)

    // ---- layer 1: 32 -> 128 ----  (NC=1, NY=1)
    convin_kernel<<<(N * 4 + 255) / 256, 256, 0, stream>>>(v, txb1, N);
    prop_kernel<32, 1><<<nbk * 1, 256, 0, stream>>>(txb1, row_ptr, ep, N);
    prop_kernel<32, 2><<<nbk * 1, 256, 0, stream>>>(txb1, row_ptr, ep, N);
    gemm_kernel<true, 1><<<mt * 1, 512, 0, stream>>>(txb1, Wt1, b1, txb2, N, 96, 128, mt * 1);

    // ---- layer 2: 128 -> 256 ----  (NC=4, NY=2)
    prop_kernel<128, 1><<<nbk * 4, 256, 0, stream>>>(txb2, row_ptr, ep, N);
    prop_kernel<128, 2><<<nbk * 4, 256, 0, stream>>>(txb2, row_ptr, ep, N);
    gemm_kernel<true, 2><<<mt * 2, 512, 0, stream>>>(txb2, Wt2, b2, txb3, N, 384, 256, mt * 2);

    // ---- layer 3: 256 -> 512 ----  (NC=8, NY=4)
    prop_kernel<256, 1><<<nbk * 8, 256, 0, stream>>>(txb3, row_ptr, ep, N);
    prop_kernel<256, 2><<<nbk * 8, 256, 0, stream>>>(txb3, row_ptr, ep, N);
    gemm_kernel<false, 4><<<mt * 4, 512, 0, stream>>>(txb3, Wt3, b3, outF, N, 768, 512, mt * 4);
}